// Round 5
// baseline (117.716 us; speedup 1.0000x reference)
//
#include <hip/hip_runtime.h>
#include <stdint.h>

typedef __bf16 bf16x8 __attribute__((ext_vector_type(8)));
typedef float f32x4 __attribute__((ext_vector_type(4)));
typedef unsigned short u16;
typedef const __attribute__((address_space(1))) void* as1_cvp;
typedef __attribute__((address_space(3))) void* as3_vp;

__device__ __forceinline__ u16 f2bf(float f) {
  union { float f; unsigned u; } v; v.f = f;
  unsigned r = v.u + 0x7fffu + ((v.u >> 16) & 1u);
  return (u16)(r >> 16);
}

// ---- idx histogram + exclusive scan (4 options) ----
__global__ __launch_bounds__(256) void hist_kernel(const int* __restrict__ idx, int n,
                            int* __restrict__ starts, int* __restrict__ cursors) {
  __shared__ int cnt[4];
  const int t = threadIdx.x;
  if (t < 4) { cnt[t] = 0; cursors[t] = 0; }
  __syncthreads();
  int c0 = 0, c1 = 0, c2 = 0, c3 = 0;
  for (int i = t; i < n; i += 256) {
    const int g = idx[i] & 3;
    c0 += (g == 0); c1 += (g == 1); c2 += (g == 2); c3 += (g == 3);
  }
  if (c0) atomicAdd(&cnt[0], c0);
  if (c1) atomicAdd(&cnt[1], c1);
  if (c2) atomicAdd(&cnt[2], c2);
  if (c3) atomicAdd(&cnt[3], c3);
  __syncthreads();
  if (t == 0) {
    int s = 0;
    for (int g = 0; g < 4; ++g) { starts[g] = s; s += cnt[g]; }
    starts[4] = s;
  }
}

// ---- per-row: rank within group, write perm, convert row to bf16 (sorted) ----
__global__ __launch_bounds__(256) void permute_convert(
    const float* __restrict__ x, const int* __restrict__ idx,
    const int* __restrict__ starts, int* cursors,
    int* __restrict__ perm, u16* __restrict__ Xs) {
  const int b = blockIdx.x;
  __shared__ int s_pos;
  if (threadIdx.x == 0) {
    const int g = idx[b] & 3;
    const int r = atomicAdd(&cursors[g], 1);
    const int p = starts[g] + r;
    perm[p] = b;
    s_pos = p;
  }
  __syncthreads();
  const int p = s_pos;
  const float4 v = ((const float4*)(x + (size_t)b * 1024))[threadIdx.x];
  ushort4 u;
  u.x = f2bf(v.x); u.y = f2bf(v.y); u.z = f2bf(v.z); u.w = f2bf(v.w);
  ((ushort4*)(Xs + (size_t)p * 1024))[threadIdx.x] = u;
}

// ---- both W transposes in one launch: W [O][K][N] f32 -> WT [O][N][K] bf16 ----
__global__ __launch_bounds__(256) void transpose_both(
    const float* __restrict__ W1, u16* __restrict__ W1T,
    const float* __restrict__ W2, u16* __restrict__ W2T) {
  __shared__ float tile[64][65];
  int bid = blockIdx.x;
  const float* W; u16* WT; int K, N, tx, ty, o;
  if (bid < 2048) {         // W1: K=1024, N=2048 -> 32x16x4 tiles
    W = W1; WT = W1T; K = 1024; N = 2048;
    o = bid >> 9; const int t = bid & 511; tx = t & 31; ty = t >> 5;
  } else {                  // W2: K=2048, N=1024 -> 16x32x4 tiles
    bid -= 2048;
    W = W2; WT = W2T; K = 2048; N = 1024;
    o = bid >> 9; const int t = bid & 511; tx = t & 15; ty = t >> 4;
  }
  const float* Wo = W + (size_t)o * K * N;
  u16* WTo = WT + (size_t)o * N * K;
  const int k0 = ty * 64, n0 = tx * 64;
  const int rr = threadIdx.x >> 4, cc = threadIdx.x & 15;
  #pragma unroll
  for (int j = 0; j < 4; ++j) {
    const int r = j * 16 + rr;
    const float4 v = *(const float4*)(Wo + (size_t)(k0 + r) * N + n0 + cc * 4);
    tile[r][cc * 4 + 0] = v.x; tile[r][cc * 4 + 1] = v.y;
    tile[r][cc * 4 + 2] = v.z; tile[r][cc * 4 + 3] = v.w;
  }
  __syncthreads();
  #pragma unroll
  for (int j = 0; j < 4; ++j) {
    const int nrow = j * 16 + rr;
    ushort4 u;
    u.x = f2bf(tile[cc * 4 + 0][nrow]);
    u.y = f2bf(tile[cc * 4 + 1][nrow]);
    u.z = f2bf(tile[cc * 4 + 2][nrow]);
    u.w = f2bf(tile[cc * 4 + 3][nrow]);
    *(ushort4*)(WTo + (size_t)(n0 + nrow) * K + k0 + cc * 4) = u;
  }
}

// ---- grouped GEMM: C[M,N] = A_sorted[M,K] @ WT[o][N,K]^T ----
// tile M128 x N128, BK=64, 4 waves (2x2), wave 64x64 (4x4 frags, kk-loop 2)
// -> 32 MFMA + 16 ds_read_b128 per wave per K-step (fat phases).
// Double-buffered LDS (2x32KB), counted vmcnt(8), T2 XOR swizzle, T5 setprio.
// EPI 0: write bf16 (sorted) + bias.  EPI 1: write f32 split-K partial.
template <int EPI, int KT, int NN, int S, int NTN, int NTM>
__global__ __launch_bounds__(256, 2) void gemm_kernel(
    const u16* __restrict__ A, const u16* __restrict__ BT,
    const float* __restrict__ bias, const int* __restrict__ starts,
    u16* __restrict__ outH, float* __restrict__ outP, int batchB) {
  // buf0: A @0 (16KB), B @16384 (16KB); buf1: A @32768, B @49152
  __shared__ char smem[65536];

  // XCD-chunked bijective swizzle (nwg % 8 == 0), n fastest -> L2 panel reuse
  const int nwg = NTN * NTM * 4 * S;
  const int q = nwg >> 3;
  const int bid = blockIdx.x;
  const int swz = (bid & 7) * q + (bid >> 3);
  const int n_t = swz % NTN;
  const int m_t = (swz / NTN) % NTM;
  const int og = swz / (NTN * NTM);
  const int o = og & 3;
  const int s = og >> 2;

  const int g0 = starts[o], g1 = starts[o + 1];
  const int m_start = g0 + m_t * 128;
  if (m_start >= g1) return;
  const int n_start = n_t * 128;
  const int kb0 = s * (KT / S);
  const u16* Bo = BT + (size_t)o * NN * KT;

  const int tid = threadIdx.x;
  const int w = tid >> 6;  // wave 0..3
  const int l = tid & 63;
  const int wm = w >> 1, wn = w & 1;
  const int l8 = l & 7, ld8 = l >> 3;

  // T2: global source column pre-swizzled so linear LDS dest holds
  // LDS[row][unit] = global[row][unit ^ (row&7)]  (16B units, 8 per 128B row)
  const int src_unit = l8 ^ (ld8 & 7);  // row&7 == ld8 for all staging rows

  // staging: 16 A-rows-groups + 16 B: per wave 4 A-loads + 4 B-loads of 1KB
  const u16* pA[4];
  #pragma unroll
  for (int j = 0; j < 4; ++j) {
    int r = m_start + (j * 4 + w) * 8 + ld8;
    if (r >= g1) r = g1 - 1;  // clamp (stores predicated at epilogue)
    pA[j] = A + (size_t)r * KT + kb0 + src_unit * 8;
  }
  const u16* pB[4];
  #pragma unroll
  for (int j = 0; j < 4; ++j) {
    const int nr = n_start + (j * 4 + w) * 8 + ld8;
    pB[j] = Bo + (size_t)nr * KT + kb0 + src_unit * 8;
  }

#define STAGE(dst_off)                                                         \
  {                                                                            \
    _Pragma("unroll")                                                          \
    for (int j = 0; j < 4; ++j)                                                \
      __builtin_amdgcn_global_load_lds((as1_cvp)pA[j],                         \
          (as3_vp)(smem + (dst_off) + (j * 4 + w) * 1024), 16, 0, 0);          \
    _Pragma("unroll")                                                          \
    for (int j = 0; j < 4; ++j)                                                \
      __builtin_amdgcn_global_load_lds((as1_cvp)pB[j],                         \
          (as3_vp)(smem + (dst_off) + 16384 + (j * 4 + w) * 1024), 16, 0, 0);  \
    _Pragma("unroll") for (int j = 0; j < 4; ++j) pA[j] += 64;                 \
    _Pragma("unroll") for (int j = 0; j < 4; ++j) pB[j] += 64;                 \
  }

  // fragment read byte offsets, T2 read-side XOR (row&7 == l&7 for frag rows)
  const int lrow = l & 15;
  const int lx = l & 7;
  const int lu = l >> 4;
  int offA[4][2], offB[4][2];
  #pragma unroll
  for (int a = 0; a < 4; ++a)
    #pragma unroll
    for (int kk = 0; kk < 2; ++kk)
      offA[a][kk] = (wm * 64 + a * 16 + lrow) * 128 + (((kk * 4 + lu) ^ lx) << 4);
  #pragma unroll
  for (int b = 0; b < 4; ++b)
    #pragma unroll
    for (int kk = 0; kk < 2; ++kk)
      offB[b][kk] = (wn * 64 + b * 16 + lrow) * 128 + (((kk * 4 + lu) ^ lx) << 4);

  f32x4 acc[4][4] = {};

  const int nK = (KT / S) >> 6;
  STAGE(0);  // prologue: tile 0 -> buf0
  for (int kt = 0; kt < nK; ++kt) {
    const int cur = (kt & 1) << 15;
    if (kt + 1 < nK) {
      STAGE(cur ^ 32768);  // next tile -> other buffer (stays in flight)
      asm volatile("s_waitcnt vmcnt(8)" ::: "memory");  // prev stage landed
    } else {
      asm volatile("s_waitcnt vmcnt(0)" ::: "memory");
    }
    __builtin_amdgcn_s_barrier();  // buf[cur] valid for all waves

    bf16x8 af[4][2], bfr[4][2];
    #pragma unroll
    for (int a = 0; a < 4; ++a)
      #pragma unroll
      for (int kk = 0; kk < 2; ++kk)
        af[a][kk] = *(const bf16x8*)(smem + cur + offA[a][kk]);
    #pragma unroll
    for (int b = 0; b < 4; ++b)
      #pragma unroll
      for (int kk = 0; kk < 2; ++kk)
        bfr[b][kk] = *(const bf16x8*)(smem + cur + 16384 + offB[b][kk]);
    asm volatile("s_waitcnt lgkmcnt(0)" ::: "memory");  // my reads done
    __builtin_amdgcn_s_barrier();  // all reads done -> next STAGE may overwrite

    __builtin_amdgcn_s_setprio(1);
    #pragma unroll
    for (int kk = 0; kk < 2; ++kk)
      #pragma unroll
      for (int a = 0; a < 4; ++a)
        #pragma unroll
        for (int b = 0; b < 4; ++b)
          acc[a][b] = __builtin_amdgcn_mfma_f32_16x16x32_bf16(af[a][kk], bfr[b][kk], acc[a][b], 0, 0, 0);
    __builtin_amdgcn_s_setprio(0);
  }
#undef STAGE

  // epilogue: C/D layout col = l&15, row = (l>>4)*4 + r  [m89-verified]
  const int col_l = l & 15;
  const int row_l = (l >> 4) << 2;
  #pragma unroll
  for (int a = 0; a < 4; ++a) {
    #pragma unroll
    for (int b = 0; b < 4; ++b) {
      const int n = n_start + wn * 64 + b * 16 + col_l;
      float bv = 0.f;
      if (EPI == 0) bv = bias[n];
      #pragma unroll
      for (int r = 0; r < 4; ++r) {
        const int p = m_start + wm * 64 + a * 16 + row_l + r;
        if (p < g1) {
          if (EPI == 0) {
            outH[(size_t)p * NN + n] = f2bf(acc[a][b][r] + bv);
          } else {
            outP[((size_t)(s * batchB + p)) * NN + n] = acc[a][b][r];
          }
        }
      }
    }
  }
}

// ---- split-K reduce + bias + scatter (deterministic fixed-order adds) ----
__global__ __launch_bounds__(256) void reduce_kernel(
    const float* __restrict__ part, const float* __restrict__ b2,
    const int* __restrict__ perm, float* __restrict__ out, int batchB) {
  const int p = blockIdx.x;
  const int t = threadIdx.x;
  const float4 v0 = ((const float4*)(part + (size_t)p * 1024))[t];
  const float4 v1 = ((const float4*)(part + (size_t)(batchB + p) * 1024))[t];
  const float4 bv = ((const float4*)b2)[t];
  float4 r;
  r.x = v0.x + v1.x + bv.x;
  r.y = v0.y + v1.y + bv.y;
  r.z = v0.z + v1.z + bv.z;
  r.w = v0.w + v1.w + bv.w;
  ((float4*)(out + (size_t)perm[p] * 1024))[t] = r;
}

extern "C" void kernel_launch(void* const* d_in, const int* in_sizes, int n_in,
                              void* d_out, int out_size, void* d_ws, size_t ws_size,
                              hipStream_t stream) {
  (void)n_in; (void)out_size; (void)ws_size;
  const float* x   = (const float*)d_in[0];
  const int*   idx = (const int*)d_in[1];
  const float* W1  = (const float*)d_in[2];
  const float* b1  = (const float*)d_in[3];
  const float* W2  = (const float*)d_in[4];
  const float* b2  = (const float*)d_in[5];
  float* out = (float*)d_out;

  const int B = in_sizes[1];  // 2048

  // workspace layout (44.05 MB; part aliases W1T which is dead after GEMM1)
  char* ws = (char*)d_ws;
  u16* W1T     = (u16*)(ws);                    // 16 MB [o][N=2048][K=1024]
  float* part  = (float*)(ws);                  // 2*B*1024 f32 = 16 MB (aliases W1T)
  u16* W2T     = (u16*)(ws + 16777216);         // 16 MB [o][N=1024][K=2048]
  u16* Xs      = (u16*)(ws + 33554432);         // B*1024 bf16 = 4 MB (sorted)
  u16* Hs      = (u16*)(ws + 37748736);         // B*2048 bf16 = 8 MB (sorted)
  int* perm    = (int*)(ws + 46137344);         // B ints
  int* starts  = (int*)(ws + 46137344 + 8192);  // 5 ints
  int* cursors = starts + 8;                    // 4 ints

  hist_kernel<<<1, 256, 0, stream>>>(idx, B, starts, cursors);
  transpose_both<<<4096, 256, 0, stream>>>(W1, W1T, W2, W2T);
  permute_convert<<<B, 256, 0, stream>>>(x, idx, starts, cursors, perm, Xs);

  // GEMM1: N=2048, K=1024. 16n x 16m x 4g = 1024 blocks (~256 useful).
  gemm_kernel<0, 1024, 2048, 1, 16, 16><<<1024, 256, 0, stream>>>(
      Xs, W1T, b1, starts, Hs, nullptr, B);
  // GEMM2: N=1024, K=2048, split-K x2. 8n x 16m x 4g x 2s = 1024 blocks (~256 useful).
  gemm_kernel<1, 2048, 1024, 2, 8, 16><<<1024, 256, 0, stream>>>(
      Hs, W2T, nullptr, starts, nullptr, part, B);
  reduce_kernel<<<B, 256, 0, stream>>>(part, b2, perm, out, B);
}

// Round 6
// 110.152 us; speedup vs baseline: 1.0687x; 1.0687x over previous
//
#include <hip/hip_runtime.h>
#include <stdint.h>

typedef __bf16 bf16x8 __attribute__((ext_vector_type(8)));
typedef float f32x4 __attribute__((ext_vector_type(4)));
typedef unsigned short u16;
typedef const __attribute__((address_space(1))) void* as1_cvp;
typedef __attribute__((address_space(3))) void* as3_vp;

__device__ __forceinline__ u16 f2bf(float f) {
  union { float f; unsigned u; } v; v.f = f;
  unsigned r = v.u + 0x7fffu + ((v.u >> 16) & 1u);
  return (u16)(r >> 16);
}

// ---- idx histogram + exclusive scan + compact m-tile map (4 options) ----
// tmap[t] = (group << 28) | m_start for each live 128-row tile; -1 = dead pad.
__global__ __launch_bounds__(256) void hist_kernel(const int* __restrict__ idx, int n,
                            int* __restrict__ starts, int* __restrict__ cursors,
                            int* __restrict__ tmap) {
  __shared__ int cnt[4];
  const int t = threadIdx.x;
  if (t < 4) { cnt[t] = 0; cursors[t] = 0; }
  __syncthreads();
  int c0 = 0, c1 = 0, c2 = 0, c3 = 0;
  for (int i = t; i < n; i += 256) {
    const int g = idx[i] & 3;
    c0 += (g == 0); c1 += (g == 1); c2 += (g == 2); c3 += (g == 3);
  }
  if (c0) atomicAdd(&cnt[0], c0);
  if (c1) atomicAdd(&cnt[1], c1);
  if (c2) atomicAdd(&cnt[2], c2);
  if (c3) atomicAdd(&cnt[3], c3);
  __syncthreads();
  if (t == 0) {
    int s = 0, nt = 0;
    for (int g = 0; g < 4; ++g) {
      starts[g] = s;
      const int c = cnt[g];
      for (int j = 0; j < c; j += 128) tmap[nt++] = (g << 28) | (s + j);
      s += c;
    }
    starts[4] = s;
    while (nt < 20) tmap[nt++] = -1;
  }
}

// ---- per-row: rank within group, write perm, convert row to bf16 (sorted) ----
__global__ __launch_bounds__(256) void permute_convert(
    const float* __restrict__ x, const int* __restrict__ idx,
    const int* __restrict__ starts, int* cursors,
    int* __restrict__ perm, u16* __restrict__ Xs) {
  const int b = blockIdx.x;
  __shared__ int s_pos;
  if (threadIdx.x == 0) {
    const int g = idx[b] & 3;
    const int r = atomicAdd(&cursors[g], 1);
    const int p = starts[g] + r;
    perm[p] = b;
    s_pos = p;
  }
  __syncthreads();
  const int p = s_pos;
  const float4 v = ((const float4*)(x + (size_t)b * 1024))[threadIdx.x];
  ushort4 u;
  u.x = f2bf(v.x); u.y = f2bf(v.y); u.z = f2bf(v.z); u.w = f2bf(v.w);
  ((ushort4*)(Xs + (size_t)p * 1024))[threadIdx.x] = u;
}

// ---- both W transposes in one launch: W [O][K][N] f32 -> WT [O][N][K] bf16 ----
__global__ __launch_bounds__(256) void transpose_both(
    const float* __restrict__ W1, u16* __restrict__ W1T,
    const float* __restrict__ W2, u16* __restrict__ W2T) {
  __shared__ float tile[64][65];
  int bid = blockIdx.x;
  const float* W; u16* WT; int K, N, tx, ty, o;
  if (bid < 2048) {         // W1: K=1024, N=2048 -> 32x16x4 tiles
    W = W1; WT = W1T; K = 1024; N = 2048;
    o = bid >> 9; const int t = bid & 511; tx = t & 31; ty = t >> 5;
  } else {                  // W2: K=2048, N=1024 -> 16x32x4 tiles
    bid -= 2048;
    W = W2; WT = W2T; K = 2048; N = 1024;
    o = bid >> 9; const int t = bid & 511; tx = t & 15; ty = t >> 4;
  }
  const float* Wo = W + (size_t)o * K * N;
  u16* WTo = WT + (size_t)o * N * K;
  const int k0 = ty * 64, n0 = tx * 64;
  const int rr = threadIdx.x >> 4, cc = threadIdx.x & 15;
  #pragma unroll
  for (int j = 0; j < 4; ++j) {
    const int r = j * 16 + rr;
    const float4 v = *(const float4*)(Wo + (size_t)(k0 + r) * N + n0 + cc * 4);
    tile[r][cc * 4 + 0] = v.x; tile[r][cc * 4 + 1] = v.y;
    tile[r][cc * 4 + 2] = v.z; tile[r][cc * 4 + 3] = v.w;
  }
  __syncthreads();
  #pragma unroll
  for (int j = 0; j < 4; ++j) {
    const int nrow = j * 16 + rr;
    ushort4 u;
    u.x = f2bf(tile[cc * 4 + 0][nrow]);
    u.y = f2bf(tile[cc * 4 + 1][nrow]);
    u.z = f2bf(tile[cc * 4 + 2][nrow]);
    u.w = f2bf(tile[cc * 4 + 3][nrow]);
    *(ushort4*)(WTo + (size_t)(n0 + nrow) * K + k0 + cc * 4) = u;
  }
}

// ---- grouped GEMM: C[M,N] = A_sorted[M,K] @ WT[o][N,K]^T ----
// Compact grid: m-tiles from tmap (only live tiles). tile M128 x N128, BK=64,
// 4 waves (2x2), wave 64x64 (4x4 frags), dbuf LDS, counted vmcnt(8), T2, T5.
// EPI 0: write bf16 (sorted) + bias.  EPI 1: write f32 split-K partial.
template <int EPI, int KT, int NN, int S, int NTN>
__global__ __launch_bounds__(256, 2) void gemm_kernel(
    const u16* __restrict__ A, const u16* __restrict__ BT,
    const float* __restrict__ bias, const int* __restrict__ starts,
    const int* __restrict__ tmap, u16* __restrict__ outH,
    float* __restrict__ outP, int batchB) {
  // buf0: A @0 (16KB), B @16384 (16KB); buf1: A @32768, B @49152
  __shared__ char smem[65536];

  constexpr int NT_PAD = 20;
  const int nwg = NT_PAD * NTN * S;      // 320, % 8 == 0
  const int q = nwg >> 3;
  const int bid = blockIdx.x;
  const int swz = (bid & 7) * q + (bid >> 3);  // XCD-chunked bijective
  const int tile = swz % NT_PAD;               // m-tile fastest: B-panel reuse in L2
  const int n_t = (swz / NT_PAD) % NTN;
  const int s = swz / (NT_PAD * NTN);

  const int tm = tmap[tile];
  if (tm < 0) return;
  const int o = tm >> 28;
  const int m_start = tm & 0x0FFFFFFF;
  const int g1 = starts[o + 1];
  const int n_start = n_t * 128;
  const int kb0 = s * (KT / S);
  const u16* Bo = BT + (size_t)o * NN * KT;

  const int tid = threadIdx.x;
  const int w = tid >> 6;  // wave 0..3
  const int l = tid & 63;
  const int wm = w >> 1, wn = w & 1;
  const int l8 = l & 7, ld8 = l >> 3;

  // T2: global source column pre-swizzled so linear LDS dest holds
  // LDS[row][unit] = global[row][unit ^ (row&7)]  (16B units, 8 per 128B row)
  const int src_unit = l8 ^ (ld8 & 7);

  const u16* pA[4];
  #pragma unroll
  for (int j = 0; j < 4; ++j) {
    int r = m_start + (j * 4 + w) * 8 + ld8;
    if (r >= g1) r = g1 - 1;  // clamp (stores predicated at epilogue)
    pA[j] = A + (size_t)r * KT + kb0 + src_unit * 8;
  }
  const u16* pB[4];
  #pragma unroll
  for (int j = 0; j < 4; ++j) {
    const int nr = n_start + (j * 4 + w) * 8 + ld8;
    pB[j] = Bo + (size_t)nr * KT + kb0 + src_unit * 8;
  }

#define STAGE(dst_off)                                                         \
  {                                                                            \
    _Pragma("unroll")                                                          \
    for (int j = 0; j < 4; ++j)                                                \
      __builtin_amdgcn_global_load_lds((as1_cvp)pA[j],                         \
          (as3_vp)(smem + (dst_off) + (j * 4 + w) * 1024), 16, 0, 0);          \
    _Pragma("unroll")                                                          \
    for (int j = 0; j < 4; ++j)                                                \
      __builtin_amdgcn_global_load_lds((as1_cvp)pB[j],                         \
          (as3_vp)(smem + (dst_off) + 16384 + (j * 4 + w) * 1024), 16, 0, 0);  \
    _Pragma("unroll") for (int j = 0; j < 4; ++j) pA[j] += 64;                 \
    _Pragma("unroll") for (int j = 0; j < 4; ++j) pB[j] += 64;                 \
  }

  // fragment read byte offsets, T2 read-side XOR (row&7 == l&7 for frag rows)
  const int lrow = l & 15;
  const int lx = l & 7;
  const int lu = l >> 4;
  int offA[4][2], offB[4][2];
  #pragma unroll
  for (int a = 0; a < 4; ++a)
    #pragma unroll
    for (int kk = 0; kk < 2; ++kk)
      offA[a][kk] = (wm * 64 + a * 16 + lrow) * 128 + (((kk * 4 + lu) ^ lx) << 4);
  #pragma unroll
  for (int b = 0; b < 4; ++b)
    #pragma unroll
    for (int kk = 0; kk < 2; ++kk)
      offB[b][kk] = (wn * 64 + b * 16 + lrow) * 128 + (((kk * 4 + lu) ^ lx) << 4);

  f32x4 acc[4][4] = {};

  const int nK = (KT / S) >> 6;
  STAGE(0);  // prologue: tile 0 -> buf0
  for (int kt = 0; kt < nK; ++kt) {
    const int cur = (kt & 1) << 15;
    if (kt + 1 < nK) {
      STAGE(cur ^ 32768);  // next tile -> other buffer (stays in flight)
      asm volatile("s_waitcnt vmcnt(8)" ::: "memory");  // prev stage landed
    } else {
      asm volatile("s_waitcnt vmcnt(0)" ::: "memory");
    }
    __builtin_amdgcn_s_barrier();  // buf[cur] valid for all waves

    bf16x8 af[4][2], bfr[4][2];
    #pragma unroll
    for (int a = 0; a < 4; ++a)
      #pragma unroll
      for (int kk = 0; kk < 2; ++kk)
        af[a][kk] = *(const bf16x8*)(smem + cur + offA[a][kk]);
    #pragma unroll
    for (int b = 0; b < 4; ++b)
      #pragma unroll
      for (int kk = 0; kk < 2; ++kk)
        bfr[b][kk] = *(const bf16x8*)(smem + cur + 16384 + offB[b][kk]);
    asm volatile("s_waitcnt lgkmcnt(0)" ::: "memory");  // my reads done
    __builtin_amdgcn_s_barrier();  // all reads done -> next STAGE may overwrite

    __builtin_amdgcn_s_setprio(1);
    #pragma unroll
    for (int kk = 0; kk < 2; ++kk)
      #pragma unroll
      for (int a = 0; a < 4; ++a)
        #pragma unroll
        for (int b = 0; b < 4; ++b)
          acc[a][b] = __builtin_amdgcn_mfma_f32_16x16x32_bf16(af[a][kk], bfr[b][kk], acc[a][b], 0, 0, 0);
    __builtin_amdgcn_s_setprio(0);
  }
#undef STAGE

  // epilogue: C/D layout col = l&15, row = (l>>4)*4 + r  [m89-verified]
  const int col_l = l & 15;
  const int row_l = (l >> 4) << 2;
  #pragma unroll
  for (int a = 0; a < 4; ++a) {
    #pragma unroll
    for (int b = 0; b < 4; ++b) {
      const int n = n_start + wn * 64 + b * 16 + col_l;
      float bv = 0.f;
      if (EPI == 0) bv = bias[n];
      #pragma unroll
      for (int r = 0; r < 4; ++r) {
        const int p = m_start + wm * 64 + a * 16 + row_l + r;
        if (p < g1) {
          if (EPI == 0) {
            outH[(size_t)p * NN + n] = f2bf(acc[a][b][r] + bv);
          } else {
            outP[((size_t)(s * batchB + p)) * NN + n] = acc[a][b][r];
          }
        }
      }
    }
  }
}

// ---- split-K reduce + bias + scatter (deterministic fixed-order adds) ----
__global__ __launch_bounds__(256) void reduce_kernel(
    const float* __restrict__ part, const float* __restrict__ b2,
    const int* __restrict__ perm, float* __restrict__ out, int batchB) {
  const int p = blockIdx.x;
  const int t = threadIdx.x;
  const float4 v0 = ((const float4*)(part + (size_t)p * 1024))[t];
  const float4 v1 = ((const float4*)(part + (size_t)(batchB + p) * 1024))[t];
  const float4 bv = ((const float4*)b2)[t];
  float4 r;
  r.x = v0.x + v1.x + bv.x;
  r.y = v0.y + v1.y + bv.y;
  r.z = v0.z + v1.z + bv.z;
  r.w = v0.w + v1.w + bv.w;
  ((float4*)(out + (size_t)perm[p] * 1024))[t] = r;
}

extern "C" void kernel_launch(void* const* d_in, const int* in_sizes, int n_in,
                              void* d_out, int out_size, void* d_ws, size_t ws_size,
                              hipStream_t stream) {
  (void)n_in; (void)out_size; (void)ws_size;
  const float* x   = (const float*)d_in[0];
  const int*   idx = (const int*)d_in[1];
  const float* W1  = (const float*)d_in[2];
  const float* b1  = (const float*)d_in[3];
  const float* W2  = (const float*)d_in[4];
  const float* b2  = (const float*)d_in[5];
  float* out = (float*)d_out;

  const int B = in_sizes[1];  // 2048

  // workspace layout (44.05 MB; part aliases W1T which is dead after GEMM1)
  char* ws = (char*)d_ws;
  u16* W1T     = (u16*)(ws);                    // 16 MB [o][N=2048][K=1024]
  float* part  = (float*)(ws);                  // 2*B*1024 f32 = 16 MB (aliases W1T)
  u16* W2T     = (u16*)(ws + 16777216);         // 16 MB [o][N=1024][K=2048]
  u16* Xs      = (u16*)(ws + 33554432);         // B*1024 bf16 = 4 MB (sorted)
  u16* Hs      = (u16*)(ws + 37748736);         // B*2048 bf16 = 8 MB (sorted)
  int* perm    = (int*)(ws + 46137344);         // B ints
  int* starts  = (int*)(ws + 46137344 + 8192);  // 5 ints
  int* cursors = starts + 8;                    // 4 ints
  int* tmap    = starts + 64;                   // 20 ints (live m-tile map)

  hist_kernel<<<1, 256, 0, stream>>>(idx, B, starts, cursors, tmap);
  transpose_both<<<4096, 256, 0, stream>>>(W1, W1T, W2, W2T);
  permute_convert<<<B, 256, 0, stream>>>(x, idx, starts, cursors, perm, Xs);

  // GEMM1: N=2048, K=1024. 20 m-tiles x 16 n-tiles = 320 blocks (~95% live).
  gemm_kernel<0, 1024, 2048, 1, 16><<<320, 256, 0, stream>>>(
      Xs, W1T, b1, starts, tmap, Hs, nullptr, B);
  // GEMM2: N=1024, K=2048, split-K x2. 20 x 8 x 2 = 320 blocks (~95% live).
  gemm_kernel<1, 2048, 1024, 2, 8><<<320, 256, 0, stream>>>(
      Hs, W2T, nullptr, starts, tmap, nullptr, part, B);
  reduce_kernel<<<B, 256, 0, stream>>>(part, b2, perm, out, B);
}

// Round 7
// 78.309 us; speedup vs baseline: 1.5032x; 1.4066x over previous
//
#include <hip/hip_runtime.h>
#include <stdint.h>

typedef __bf16 bf16x8 __attribute__((ext_vector_type(8)));
typedef float f32x4 __attribute__((ext_vector_type(4)));
typedef unsigned short u16;
typedef const __attribute__((address_space(1))) void* as1_cvp;
typedef __attribute__((address_space(3))) void* as3_vp;

__device__ __forceinline__ u16 f2bf(float f) {
  union { float f; unsigned u; } v; v.f = f;
  unsigned r = v.u + 0x7fffu + ((v.u >> 16) & 1u);
  return (u16)(r >> 16);
}

// ---- single-block: histogram + stable counting-sort perm + tile map ----
// No atomics: per-thread counts -> wave-per-group shfl exclusive scan.
__global__ __launch_bounds__(256) void hist_perm_kernel(
    const int* __restrict__ idx, int n, int* __restrict__ starts,
    int* __restrict__ perm, int* __restrict__ tmap) {
  __shared__ int cnt[4][256];
  __shared__ int gtot[4], gstart[4];
  const int t = threadIdx.x;
  const int rpt = (n + 255) >> 8;  // rows per thread (8 @ n=2048)
  const int base = t * rpt;
  int c[4] = {0, 0, 0, 0};
  for (int j = 0; j < rpt; ++j) {
    const int i = base + j;
    if (i < n) c[idx[i] & 3]++;
  }
  #pragma unroll
  for (int g = 0; g < 4; ++g) cnt[g][t] = c[g];
  __syncthreads();

  // wave w handles group w: 64 lanes, each covering 4 consecutive threads
  const int w = t >> 6, l = t & 63;
  {
    const int s0 = cnt[w][l * 4 + 0], s1 = cnt[w][l * 4 + 1];
    const int s2 = cnt[w][l * 4 + 2], s3 = cnt[w][l * 4 + 3];
    const int sum = s0 + s1 + s2 + s3;
    int sc = sum;  // inclusive scan over 64 lanes
    #pragma unroll
    for (int d = 1; d < 64; d <<= 1) {
      const int o = __shfl_up(sc, d, 64);
      if (l >= d) sc += o;
    }
    const int ex = sc - sum;  // exclusive
    cnt[w][l * 4 + 0] = ex;
    cnt[w][l * 4 + 1] = ex + s0;
    cnt[w][l * 4 + 2] = ex + s0 + s1;
    cnt[w][l * 4 + 3] = ex + s0 + s1 + s2;
    if (l == 63) gtot[w] = sc;
  }
  __syncthreads();

  if (t == 0) {
    int s = 0, nt = 0;
    for (int g = 0; g < 4; ++g) {
      gstart[g] = s;
      starts[g] = s;
      const int cg = gtot[g];
      for (int j = 0; j < cg; j += 128) tmap[nt++] = (g << 28) | (s + j);
      s += cg;
    }
    starts[4] = s;
    while (nt < 20) tmap[nt++] = -1;
  }
  __syncthreads();

  int run[4] = {0, 0, 0, 0};
  for (int j = 0; j < rpt; ++j) {
    const int i = base + j;
    if (i < n) {
      const int g = idx[i] & 3;
      perm[gstart[g] + cnt[g][t] + run[g]] = i;
      run[g]++;
    }
  }
}

// ---- gather + f32->bf16 convert into sorted order (atomic-free) ----
__global__ __launch_bounds__(256) void gather_convert(
    const float* __restrict__ x, const int* __restrict__ perm,
    u16* __restrict__ Xs) {
  const int p = blockIdx.x;
  const int b = perm[p];
  const float4 v = ((const float4*)(x + (size_t)b * 1024))[threadIdx.x];
  ushort4 u;
  u.x = f2bf(v.x); u.y = f2bf(v.y); u.z = f2bf(v.z); u.w = f2bf(v.w);
  ((ushort4*)(Xs + (size_t)p * 1024))[threadIdx.x] = u;
}

// ---- both W transposes in one launch: W [O][K][N] f32 -> WT [O][N][K] bf16 ----
__global__ __launch_bounds__(256) void transpose_both(
    const float* __restrict__ W1, u16* __restrict__ W1T,
    const float* __restrict__ W2, u16* __restrict__ W2T) {
  __shared__ float tile[64][65];
  int bid = blockIdx.x;
  const float* W; u16* WT; int K, N, tx, ty, o;
  if (bid < 2048) {         // W1: K=1024, N=2048 -> 32x16x4 tiles
    W = W1; WT = W1T; K = 1024; N = 2048;
    o = bid >> 9; const int t = bid & 511; tx = t & 31; ty = t >> 5;
  } else {                  // W2: K=2048, N=1024 -> 16x32x4 tiles
    bid -= 2048;
    W = W2; WT = W2T; K = 2048; N = 1024;
    o = bid >> 9; const int t = bid & 511; tx = t & 15; ty = t >> 4;
  }
  const float* Wo = W + (size_t)o * K * N;
  u16* WTo = WT + (size_t)o * N * K;
  const int k0 = ty * 64, n0 = tx * 64;
  const int rr = threadIdx.x >> 4, cc = threadIdx.x & 15;
  #pragma unroll
  for (int j = 0; j < 4; ++j) {
    const int r = j * 16 + rr;
    const float4 v = *(const float4*)(Wo + (size_t)(k0 + r) * N + n0 + cc * 4);
    tile[r][cc * 4 + 0] = v.x; tile[r][cc * 4 + 1] = v.y;
    tile[r][cc * 4 + 2] = v.z; tile[r][cc * 4 + 3] = v.w;
  }
  __syncthreads();
  #pragma unroll
  for (int j = 0; j < 4; ++j) {
    const int nrow = j * 16 + rr;
    ushort4 u;
    u.x = f2bf(tile[cc * 4 + 0][nrow]);
    u.y = f2bf(tile[cc * 4 + 1][nrow]);
    u.z = f2bf(tile[cc * 4 + 2][nrow]);
    u.w = f2bf(tile[cc * 4 + 3][nrow]);
    *(ushort4*)(WTo + (size_t)(n0 + nrow) * K + k0 + cc * 4) = u;
  }
}

// ---- grouped GEMM: C[M,N] = A_sorted[M,K] @ WT[o][N,K]^T ----
// Compact grid: m-tiles from tmap (only live tiles). tile M128 x N128, BK=64,
// 4 waves (2x2), wave 64x64 (4x4 frags), dbuf LDS, counted vmcnt(8), T2, T5.
// EPI 0: write bf16 (sorted) + bias.  EPI 1: write f32 split-K partial.
template <int EPI, int KT, int NN, int S, int NTN>
__global__ __launch_bounds__(256, 2) void gemm_kernel(
    const u16* __restrict__ A, const u16* __restrict__ BT,
    const float* __restrict__ bias, const int* __restrict__ starts,
    const int* __restrict__ tmap, u16* __restrict__ outH,
    float* __restrict__ outP, int batchB) {
  // buf0: A @0 (16KB), B @16384 (16KB); buf1: A @32768, B @49152
  __shared__ char smem[65536];

  constexpr int NT_PAD = 20;
  const int nwg = NT_PAD * NTN * S;      // 320, % 8 == 0
  const int q = nwg >> 3;
  const int bid = blockIdx.x;
  const int swz = (bid & 7) * q + (bid >> 3);  // XCD-chunked bijective
  const int tile = swz % NT_PAD;               // m-tile fastest: B-panel reuse in L2
  const int n_t = (swz / NT_PAD) % NTN;
  const int s = swz / (NT_PAD * NTN);

  const int tm = tmap[tile];
  if (tm < 0) return;
  const int o = tm >> 28;
  const int m_start = tm & 0x0FFFFFFF;
  const int g1 = starts[o + 1];
  const int n_start = n_t * 128;
  const int kb0 = s * (KT / S);
  const u16* Bo = BT + (size_t)o * NN * KT;

  const int tid = threadIdx.x;
  const int w = tid >> 6;  // wave 0..3
  const int l = tid & 63;
  const int wm = w >> 1, wn = w & 1;
  const int l8 = l & 7, ld8 = l >> 3;

  // T2: global source column pre-swizzled so linear LDS dest holds
  // LDS[row][unit] = global[row][unit ^ (row&7)]  (16B units, 8 per 128B row)
  const int src_unit = l8 ^ (ld8 & 7);

  const u16* pA[4];
  #pragma unroll
  for (int j = 0; j < 4; ++j) {
    int r = m_start + (j * 4 + w) * 8 + ld8;
    if (r >= g1) r = g1 - 1;  // clamp (stores predicated at epilogue)
    pA[j] = A + (size_t)r * KT + kb0 + src_unit * 8;
  }
  const u16* pB[4];
  #pragma unroll
  for (int j = 0; j < 4; ++j) {
    const int nr = n_start + (j * 4 + w) * 8 + ld8;
    pB[j] = Bo + (size_t)nr * KT + kb0 + src_unit * 8;
  }

#define STAGE(dst_off)                                                         \
  {                                                                            \
    _Pragma("unroll")                                                          \
    for (int j = 0; j < 4; ++j)                                                \
      __builtin_amdgcn_global_load_lds((as1_cvp)pA[j],                         \
          (as3_vp)(smem + (dst_off) + (j * 4 + w) * 1024), 16, 0, 0);          \
    _Pragma("unroll")                                                          \
    for (int j = 0; j < 4; ++j)                                                \
      __builtin_amdgcn_global_load_lds((as1_cvp)pB[j],                         \
          (as3_vp)(smem + (dst_off) + 16384 + (j * 4 + w) * 1024), 16, 0, 0);  \
    _Pragma("unroll") for (int j = 0; j < 4; ++j) pA[j] += 64;                 \
    _Pragma("unroll") for (int j = 0; j < 4; ++j) pB[j] += 64;                 \
  }

  // fragment read byte offsets, T2 read-side XOR (row&7 == l&7 for frag rows)
  const int lrow = l & 15;
  const int lx = l & 7;
  const int lu = l >> 4;
  int offA[4][2], offB[4][2];
  #pragma unroll
  for (int a = 0; a < 4; ++a)
    #pragma unroll
    for (int kk = 0; kk < 2; ++kk)
      offA[a][kk] = (wm * 64 + a * 16 + lrow) * 128 + (((kk * 4 + lu) ^ lx) << 4);
  #pragma unroll
  for (int b = 0; b < 4; ++b)
    #pragma unroll
    for (int kk = 0; kk < 2; ++kk)
      offB[b][kk] = (wn * 64 + b * 16 + lrow) * 128 + (((kk * 4 + lu) ^ lx) << 4);

  f32x4 acc[4][4] = {};

  const int nK = (KT / S) >> 6;
  STAGE(0);  // prologue: tile 0 -> buf0
  for (int kt = 0; kt < nK; ++kt) {
    const int cur = (kt & 1) << 15;
    if (kt + 1 < nK) {
      STAGE(cur ^ 32768);  // next tile -> other buffer (stays in flight)
      asm volatile("s_waitcnt vmcnt(8)" ::: "memory");  // prev stage landed
    } else {
      asm volatile("s_waitcnt vmcnt(0)" ::: "memory");
    }
    __builtin_amdgcn_s_barrier();  // buf[cur] valid for all waves

    bf16x8 af[4][2], bfr[4][2];
    #pragma unroll
    for (int a = 0; a < 4; ++a)
      #pragma unroll
      for (int kk = 0; kk < 2; ++kk)
        af[a][kk] = *(const bf16x8*)(smem + cur + offA[a][kk]);
    #pragma unroll
    for (int b = 0; b < 4; ++b)
      #pragma unroll
      for (int kk = 0; kk < 2; ++kk)
        bfr[b][kk] = *(const bf16x8*)(smem + cur + 16384 + offB[b][kk]);
    asm volatile("s_waitcnt lgkmcnt(0)" ::: "memory");  // my reads done
    __builtin_amdgcn_s_barrier();  // all reads done -> next STAGE may overwrite

    __builtin_amdgcn_s_setprio(1);
    #pragma unroll
    for (int kk = 0; kk < 2; ++kk)
      #pragma unroll
      for (int a = 0; a < 4; ++a)
        #pragma unroll
        for (int b = 0; b < 4; ++b)
          acc[a][b] = __builtin_amdgcn_mfma_f32_16x16x32_bf16(af[a][kk], bfr[b][kk], acc[a][b], 0, 0, 0);
    __builtin_amdgcn_s_setprio(0);
  }
#undef STAGE

  // epilogue: C/D layout col = l&15, row = (l>>4)*4 + r  [m89-verified]
  const int col_l = l & 15;
  const int row_l = (l >> 4) << 2;
  #pragma unroll
  for (int a = 0; a < 4; ++a) {
    #pragma unroll
    for (int b = 0; b < 4; ++b) {
      const int n = n_start + wn * 64 + b * 16 + col_l;
      float bv = 0.f;
      if (EPI == 0) bv = bias[n];
      #pragma unroll
      for (int r = 0; r < 4; ++r) {
        const int p = m_start + wm * 64 + a * 16 + row_l + r;
        if (p < g1) {
          if (EPI == 0) {
            outH[(size_t)p * NN + n] = f2bf(acc[a][b][r] + bv);
          } else {
            outP[((size_t)(s * batchB + p)) * NN + n] = acc[a][b][r];
          }
        }
      }
    }
  }
}

// ---- split-K reduce + bias + scatter (deterministic fixed-order adds) ----
__global__ __launch_bounds__(256) void reduce_kernel(
    const float* __restrict__ part, const float* __restrict__ b2,
    const int* __restrict__ perm, float* __restrict__ out, int batchB) {
  const int p = blockIdx.x;
  const int t = threadIdx.x;
  const float4 v0 = ((const float4*)(part + (size_t)p * 1024))[t];
  const float4 v1 = ((const float4*)(part + (size_t)(batchB + p) * 1024))[t];
  const float4 bv = ((const float4*)b2)[t];
  float4 r;
  r.x = v0.x + v1.x + bv.x;
  r.y = v0.y + v1.y + bv.y;
  r.z = v0.z + v1.z + bv.z;
  r.w = v0.w + v1.w + bv.w;
  ((float4*)(out + (size_t)perm[p] * 1024))[t] = r;
}

extern "C" void kernel_launch(void* const* d_in, const int* in_sizes, int n_in,
                              void* d_out, int out_size, void* d_ws, size_t ws_size,
                              hipStream_t stream) {
  (void)n_in; (void)out_size; (void)ws_size;
  const float* x   = (const float*)d_in[0];
  const int*   idx = (const int*)d_in[1];
  const float* W1  = (const float*)d_in[2];
  const float* b1  = (const float*)d_in[3];
  const float* W2  = (const float*)d_in[4];
  const float* b2  = (const float*)d_in[5];
  float* out = (float*)d_out;

  const int B = in_sizes[1];  // 2048

  // workspace layout (44.05 MB; part aliases W1T which is dead after GEMM1)
  char* ws = (char*)d_ws;
  u16* W1T     = (u16*)(ws);                    // 16 MB [o][N=2048][K=1024]
  float* part  = (float*)(ws);                  // 2*B*1024 f32 = 16 MB (aliases W1T)
  u16* W2T     = (u16*)(ws + 16777216);         // 16 MB [o][N=1024][K=2048]
  u16* Xs      = (u16*)(ws + 33554432);         // B*1024 bf16 = 4 MB (sorted)
  u16* Hs      = (u16*)(ws + 37748736);         // B*2048 bf16 = 8 MB (sorted)
  int* perm    = (int*)(ws + 46137344);         // B ints
  int* starts  = (int*)(ws + 46137344 + 8192);  // 5 ints
  int* tmap    = starts + 64;                   // 20 ints (live m-tile map)

  hist_perm_kernel<<<1, 256, 0, stream>>>(idx, B, starts, perm, tmap);
  transpose_both<<<4096, 256, 0, stream>>>(W1, W1T, W2, W2T);
  gather_convert<<<B, 256, 0, stream>>>(x, perm, Xs);

  // GEMM1: N=2048, K=1024. 20 m-tiles x 16 n-tiles = 320 blocks (~95% live).
  gemm_kernel<0, 1024, 2048, 1, 16><<<320, 256, 0, stream>>>(
      Xs, W1T, b1, starts, tmap, Hs, nullptr, B);
  // GEMM2: N=1024, K=2048, split-K x2. 20 x 8 x 2 = 320 blocks (~95% live).
  gemm_kernel<1, 2048, 1024, 2, 8><<<320, 256, 0, stream>>>(
      Hs, W2T, nullptr, starts, tmap, nullptr, part, B);
  reduce_kernel<<<B, 256, 0, stream>>>(part, b2, perm, out, B);
}